// Round 1
// baseline (268.065 us; speedup 1.0000x reference)
//
#include <hip/hip_runtime.h>
#include <hip/hip_bf16.h>

#define BN 8192
#define DIM 512
#define EPSF 1e-8f

using frag8 = __attribute__((ext_vector_type(8))) short;   // 8 bf16 (4 VGPRs)
using f32x4 = __attribute__((ext_vector_type(4))) float;   // 4 fp32 acc

__device__ inline unsigned short f2bf(float f) {
    union { float f; unsigned int u; } x; x.f = f;
    unsigned int r = (x.u + 0x7FFFu + ((x.u >> 16) & 1u)) >> 16;
    return (unsigned short)r;
}

// One wave per row: L2-normalize and convert to bf16.
__global__ __launch_bounds__(256) void normalize_kernel(
        const float* __restrict__ emb, unsigned short* __restrict__ E) {
    int wave = threadIdx.x >> 6;
    int lane = threadIdx.x & 63;
    int row  = blockIdx.x * 4 + wave;
    const float4* src = (const float4*)(emb + (size_t)row * DIM);
    float4 a = src[lane * 2 + 0];
    float4 b = src[lane * 2 + 1];
    float ss = a.x*a.x + a.y*a.y + a.z*a.z + a.w*a.w
             + b.x*b.x + b.y*b.y + b.z*b.z + b.w*b.w;
    #pragma unroll
    for (int m = 1; m < 64; m <<= 1) ss += __shfl_xor(ss, m, 64);
    float scale = 1.0f / fmaxf(sqrtf(ss), 1e-12f);
    unsigned short u[8];
    u[0] = f2bf(a.x*scale); u[1] = f2bf(a.y*scale);
    u[2] = f2bf(a.z*scale); u[3] = f2bf(a.w*scale);
    u[4] = f2bf(b.x*scale); u[5] = f2bf(b.y*scale);
    u[6] = f2bf(b.z*scale); u[7] = f2bf(b.w*scale);
    uint4 packed;
    packed.x = (unsigned)u[0] | ((unsigned)u[1] << 16);
    packed.y = (unsigned)u[2] | ((unsigned)u[3] << 16);
    packed.z = (unsigned)u[4] | ((unsigned)u[5] << 16);
    packed.w = (unsigned)u[6] | ((unsigned)u[7] << 16);
    *(uint4*)(E + (size_t)row * DIM + lane * 8) = packed;
}

// 128x128 block tile, 4 waves, each wave 64x64 via 4x4 grid of 16x16x32 MFMA.
// Fused epilogue: w = exp(S-1), label-masked row sums -> atomicAdd to pos/neg.
__global__ __launch_bounds__(256) void gemm_epi_kernel(
        const unsigned short* __restrict__ E, const int* __restrict__ labels,
        float* __restrict__ pos, float* __restrict__ neg) {
    constexpr int BI = 128, BJ = 128, BK = 32;
    __shared__ unsigned short As[BI][BK];   // 8 KB
    __shared__ unsigned short Bs[BJ][BK];   // 8 KB
    __shared__ int labI[BI];
    __shared__ int labJ[BJ];

    const int tid  = threadIdx.x;
    const int i0   = blockIdx.y * BI;
    const int j0   = blockIdx.x * BJ;
    const int wave = tid >> 6;
    const int lane = tid & 63;
    const int quad = lane >> 4;    // 0..3
    const int lrow = lane & 15;    // 0..15
    const int i_w  = (wave >> 1) * 64;
    const int j_w  = (wave & 1) * 64;

    if (tid < 128)       labI[tid]        = labels[i0 + tid];
    else                 labJ[tid - 128]  = labels[j0 + tid - 128];

    f32x4 acc[4][4];
    #pragma unroll
    for (int a = 0; a < 4; ++a)
        #pragma unroll
        for (int b = 0; b < 4; ++b)
            acc[a][b] = (f32x4){0.f, 0.f, 0.f, 0.f};

    const uint4* Eg = (const uint4*)E;   // row stride = DIM/8 = 64 uint4
    const int rowT = tid >> 2;           // 0..63
    const int colc = tid & 3;            // 0..3, 8 bf16 each

    for (int kk = 0; kk < DIM; kk += BK) {
        __syncthreads();
        #pragma unroll
        for (int h = 0; h < 2; ++h) {
            int r = rowT + h * 64;
            uint4 va = Eg[(size_t)(i0 + r) * 64 + (kk >> 3) + colc];
            uint4 vb = Eg[(size_t)(j0 + r) * 64 + (kk >> 3) + colc];
            *(uint4*)&As[r][colc * 8] = va;
            *(uint4*)&Bs[r][colc * 8] = vb;
        }
        __syncthreads();

        frag8 af[4], bf[4];
        #pragma unroll
        for (int t = 0; t < 4; ++t) {
            af[t] = *(const frag8*)&As[i_w + t * 16 + lrow][quad * 8];
            bf[t] = *(const frag8*)&Bs[j_w + t * 16 + lrow][quad * 8];
        }
        #pragma unroll
        for (int ti = 0; ti < 4; ++ti)
            #pragma unroll
            for (int tj = 0; tj < 4; ++tj)
                acc[ti][tj] = __builtin_amdgcn_mfma_f32_16x16x32_bf16(
                                  af[ti], bf[tj], acc[ti][tj], 0, 0, 0);
    }

    // Epilogue: C/D layout col = lane&15, row = quad*4 + reg.
    #pragma unroll
    for (int ti = 0; ti < 4; ++ti) {
        #pragma unroll
        for (int reg = 0; reg < 4; ++reg) {
            int irow = i_w + ti * 16 + quad * 4 + reg;
            int li   = labI[irow];
            int gi   = i0 + irow;
            float ps = 0.f, ns = 0.f;
            #pragma unroll
            for (int tj = 0; tj < 4; ++tj) {
                int jcol = j_w + tj * 16 + lrow;
                int lj   = labJ[jcol];
                int gj   = j0 + jcol;
                float s  = acc[ti][tj][reg];
                float w  = __expf(s - 1.0f);
                bool same = (li == lj);
                ps += (same && (gi != gj)) ? w : 0.f;
                ns += (!same) ? w : 0.f;
            }
            #pragma unroll
            for (int m = 1; m < 16; m <<= 1) {
                ps += __shfl_xor(ps, m, 64);
                ns += __shfl_xor(ns, m, 64);
            }
            if (lrow == 0) {
                atomicAdd(&pos[gi], ps);
                atomicAdd(&neg[gi], ns);
            }
        }
    }
}

// Single block: histogram of 128 classes, per-row loss, mean.
__global__ __launch_bounds__(1024) void finalize_kernel(
        const int* __restrict__ labels, const float* __restrict__ pos,
        const float* __restrict__ neg, float* __restrict__ out) {
    __shared__ int cnt[128];
    __shared__ float wsum[16];
    int tid = threadIdx.x;
    if (tid < 128) cnt[tid] = 0;
    __syncthreads();
    for (int i = tid; i < BN; i += 1024) atomicAdd(&cnt[labels[i]], 1);
    __syncthreads();
    float local = 0.f;
    for (int i = tid; i < BN; i += 1024) {
        int c = cnt[labels[i]];
        float pc = (float)(c - 1);
        float nc = (float)(BN - c);
        float pm = pos[i] / fmaxf(pc, 1.0f);
        float nm = neg[i] / fmaxf(nc, 1.0f);
        float v = ((c - 1 > 0) && (BN - c > 0))
                      ? -logf(pm / (pm + nm + EPSF)) : 0.0f;
        local += v;
    }
    #pragma unroll
    for (int m = 1; m < 64; m <<= 1) local += __shfl_xor(local, m, 64);
    if ((tid & 63) == 0) wsum[tid >> 6] = local;
    __syncthreads();
    if (tid < 16) {
        float v = wsum[tid];
        #pragma unroll
        for (int m = 1; m < 16; m <<= 1) v += __shfl_xor(v, m, 64);
        if (tid == 0) out[0] = v / (float)BN;
    }
}

extern "C" void kernel_launch(void* const* d_in, const int* in_sizes, int n_in,
                              void* d_out, int out_size, void* d_ws, size_t ws_size,
                              hipStream_t stream) {
    const float* emb   = (const float*)d_in[0];
    const int* labels  = (const int*)d_in[1];
    float* out         = (float*)d_out;

    unsigned short* E  = (unsigned short*)d_ws;                      // 8 MB bf16
    float* pos         = (float*)((char*)d_ws + (size_t)BN * DIM * 2);
    float* neg         = pos + BN;

    hipMemsetAsync(pos, 0, 2 * BN * sizeof(float), stream);
    normalize_kernel<<<BN / 4, 256, 0, stream>>>(emb, E);
    gemm_epi_kernel<<<dim3(BN / 128, BN / 128), 256, 0, stream>>>(E, labels, pos, neg);
    finalize_kernel<<<1, 1024, 0, stream>>>(labels, pos, neg, out);
}

// Round 2
// 211.392 us; speedup vs baseline: 1.2681x; 1.2681x over previous
//
#include <hip/hip_runtime.h>
#include <hip/hip_bf16.h>

#define BN 8192
#define DIM 512
#define EPSF 1e-8f

using frag8 = __attribute__((ext_vector_type(8))) short;   // 8 bf16 (4 VGPRs)
using f32x4 = __attribute__((ext_vector_type(4))) float;   // 4 fp32 acc

__device__ inline unsigned short f2bf(float f) {
    union { float f; unsigned int u; } x; x.f = f;
    unsigned int r = (x.u + 0x7FFFu + ((x.u >> 16) & 1u)) >> 16;
    return (unsigned short)r;
}

// Async global->LDS, 16 B per lane, dest = uniform base + lane*16.
__device__ inline void async_copy16(const unsigned short* g, unsigned short* l) {
    __builtin_amdgcn_global_load_lds(
        (const __attribute__((address_space(1))) void*)g,
        (__attribute__((address_space(3))) void*)l,
        16, 0, 0);
}

// One wave per row: L2-normalize and convert to bf16.
__global__ __launch_bounds__(256) void normalize_kernel(
        const float* __restrict__ emb, unsigned short* __restrict__ E) {
    int wave = threadIdx.x >> 6;
    int lane = threadIdx.x & 63;
    int row  = blockIdx.x * 4 + wave;
    const float4* src = (const float4*)(emb + (size_t)row * DIM);
    float4 a = src[lane * 2 + 0];
    float4 b = src[lane * 2 + 1];
    float ss = a.x*a.x + a.y*a.y + a.z*a.z + a.w*a.w
             + b.x*b.x + b.y*b.y + b.z*b.z + b.w*b.w;
    #pragma unroll
    for (int m = 1; m < 64; m <<= 1) ss += __shfl_xor(ss, m, 64);
    float scale = 1.0f / fmaxf(sqrtf(ss), 1e-12f);
    unsigned short u[8];
    u[0] = f2bf(a.x*scale); u[1] = f2bf(a.y*scale);
    u[2] = f2bf(a.z*scale); u[3] = f2bf(a.w*scale);
    u[4] = f2bf(b.x*scale); u[5] = f2bf(b.y*scale);
    u[6] = f2bf(b.z*scale); u[7] = f2bf(b.w*scale);
    uint4 packed;
    packed.x = (unsigned)u[0] | ((unsigned)u[1] << 16);
    packed.y = (unsigned)u[2] | ((unsigned)u[3] << 16);
    packed.z = (unsigned)u[4] | ((unsigned)u[5] << 16);
    packed.w = (unsigned)u[6] | ((unsigned)u[7] << 16);
    *(uint4*)(E + (size_t)row * DIM + lane * 8) = packed;
}

// Upper-triangle 128x128 block tiles (bi <= bj). 4 waves, each wave 64x64 via
// 4x4 grid of 16x16x32 MFMA. global_load_lds staging (16 B / lane).
// Fused epilogue: w = exp(S-1); row sums -> rows i; for off-diagonal blocks,
// column sums (symmetry) -> rows j.
__global__ __launch_bounds__(256) void gemm_epi_kernel(
        const unsigned short* __restrict__ E, const int* __restrict__ labels,
        float* __restrict__ pos, float* __restrict__ neg) {
    constexpr int BI = 128, BJ = 128, BK = 32;

    const int bi = blockIdx.y, bj = blockIdx.x;
    if (bi > bj) return;               // symmetry: only upper triangle
    const bool diag = (bi == bj);

    __shared__ unsigned short As[BI][BK];   // 8 KB, row = 64 B
    __shared__ unsigned short Bs[BJ][BK];   // 8 KB
    __shared__ int labI[BI];
    __shared__ int labJ[BJ];

    const int tid  = threadIdx.x;
    const int i0   = bi * BI;
    const int j0   = bj * BJ;
    const int wave = tid >> 6;
    const int lane = tid & 63;
    const int quad = lane >> 4;    // 0..3
    const int lrow = lane & 15;    // 0..15
    const int i_w  = (wave >> 1) * 64;
    const int j_w  = (wave & 1) * 64;

    if (tid < 128)       labI[tid]        = labels[i0 + tid];
    else                 labJ[tid - 128]  = labels[j0 + tid - 128];

    f32x4 acc[4][4];
    #pragma unroll
    for (int a = 0; a < 4; ++a)
        #pragma unroll
        for (int b = 0; b < 4; ++b)
            acc[a][b] = (f32x4){0.f, 0.f, 0.f, 0.f};

    // Staging geometry: each wave covers rows [wave*32, wave*32+32), two
    // global_load_lds per tile (16 rows each). Lane l: row=l>>2, 16B seg=l&3.
    const int rbase = wave * 32;
    const int rowl  = lane >> 2;        // 0..15
    const int cseg  = (lane & 3) * 8;   // bf16-element offset in row

    for (int kk = 0; kk < DIM; kk += BK) {
        __syncthreads();
        #pragma unroll
        for (int h = 0; h < 2; ++h) {
            int r = rbase + h * 16;
            async_copy16(E + (size_t)(i0 + r + rowl) * DIM + kk + cseg, &As[r][0]);
            async_copy16(E + (size_t)(j0 + r + rowl) * DIM + kk + cseg, &Bs[r][0]);
        }
        __syncthreads();

        frag8 af[4], bf[4];
        #pragma unroll
        for (int t = 0; t < 4; ++t) {
            af[t] = *(const frag8*)&As[i_w + t * 16 + lrow][quad * 8];
            bf[t] = *(const frag8*)&Bs[j_w + t * 16 + lrow][quad * 8];
        }
        #pragma unroll
        for (int ti = 0; ti < 4; ++ti)
            #pragma unroll
            for (int tj = 0; tj < 4; ++tj)
                acc[ti][tj] = __builtin_amdgcn_mfma_f32_16x16x32_bf16(
                                  af[ti], bf[tj], acc[ti][tj], 0, 0, 0);
    }

    // Epilogue. C/D layout: col = lane&15, row = quad*4 + reg.
    float psC[4] = {0.f, 0.f, 0.f, 0.f};
    float nsC[4] = {0.f, 0.f, 0.f, 0.f};
    #pragma unroll
    for (int ti = 0; ti < 4; ++ti) {
        #pragma unroll
        for (int reg = 0; reg < 4; ++reg) {
            int irow = i_w + ti * 16 + quad * 4 + reg;
            int li   = labI[irow];
            int gi   = i0 + irow;
            float ps = 0.f, ns = 0.f;
            #pragma unroll
            for (int tj = 0; tj < 4; ++tj) {
                int jcol = j_w + tj * 16 + lrow;
                int lj   = labJ[jcol];
                int gj   = j0 + jcol;
                float w  = __expf(acc[ti][tj][reg] - 1.0f);
                bool same = (li == lj);
                float wp = (same && (gi != gj)) ? w : 0.f;
                float wn = same ? 0.f : w;
                ps += wp;  ns += wn;
                psC[tj] += wp;  nsC[tj] += wn;   // col sums (off-diag use)
            }
            #pragma unroll
            for (int m = 1; m < 16; m <<= 1) {
                ps += __shfl_xor(ps, m, 64);
                ns += __shfl_xor(ns, m, 64);
            }
            if (lrow == 0) {
                atomicAdd(&pos[gi], ps);
                atomicAdd(&neg[gi], ns);
            }
        }
    }
    if (!diag) {
        #pragma unroll
        for (int tj = 0; tj < 4; ++tj) {
            float ps = psC[tj], ns = nsC[tj];
            ps += __shfl_xor(ps, 16, 64);  ns += __shfl_xor(ns, 16, 64);
            ps += __shfl_xor(ps, 32, 64);  ns += __shfl_xor(ns, 32, 64);
            if (lane < 16) {
                int gj = j0 + j_w + tj * 16 + lrow;
                atomicAdd(&pos[gj], ps);
                atomicAdd(&neg[gj], ns);
            }
        }
    }
}

// Single block: histogram of 128 classes, per-row loss, mean.
__global__ __launch_bounds__(1024) void finalize_kernel(
        const int* __restrict__ labels, const float* __restrict__ pos,
        const float* __restrict__ neg, float* __restrict__ out) {
    __shared__ int cnt[128];
    __shared__ float wsum[16];
    int tid = threadIdx.x;
    if (tid < 128) cnt[tid] = 0;
    __syncthreads();
    for (int i = tid; i < BN; i += 1024) atomicAdd(&cnt[labels[i]], 1);
    __syncthreads();
    float local = 0.f;
    for (int i = tid; i < BN; i += 1024) {
        int c = cnt[labels[i]];
        float pc = (float)(c - 1);
        float nc = (float)(BN - c);
        float pm = pos[i] / fmaxf(pc, 1.0f);
        float nm = neg[i] / fmaxf(nc, 1.0f);
        float v = ((c - 1 > 0) && (BN - c > 0))
                      ? -logf(pm / (pm + nm + EPSF)) : 0.0f;
        local += v;
    }
    #pragma unroll
    for (int m = 1; m < 64; m <<= 1) local += __shfl_xor(local, m, 64);
    if ((tid & 63) == 0) wsum[tid >> 6] = local;
    __syncthreads();
    if (tid < 16) {
        float v = wsum[tid];
        #pragma unroll
        for (int m = 1; m < 16; m <<= 1) v += __shfl_xor(v, m, 64);
        if (tid == 0) out[0] = v / (float)BN;
    }
}

extern "C" void kernel_launch(void* const* d_in, const int* in_sizes, int n_in,
                              void* d_out, int out_size, void* d_ws, size_t ws_size,
                              hipStream_t stream) {
    const float* emb   = (const float*)d_in[0];
    const int* labels  = (const int*)d_in[1];
    float* out         = (float*)d_out;

    unsigned short* E  = (unsigned short*)d_ws;                      // 8 MB bf16
    float* pos         = (float*)((char*)d_ws + (size_t)BN * DIM * 2);
    float* neg         = pos + BN;

    hipMemsetAsync(pos, 0, 2 * BN * sizeof(float), stream);
    normalize_kernel<<<BN / 4, 256, 0, stream>>>(emb, E);
    gemm_epi_kernel<<<dim3(BN / 128, BN / 128), 256, 0, stream>>>(E, labels, pos, neg);
    finalize_kernel<<<1, 1024, 0, stream>>>(labels, pos, neg, out);
}

// Round 3
// 156.462 us; speedup vs baseline: 1.7133x; 1.3511x over previous
//
#include <hip/hip_runtime.h>
#include <hip/hip_bf16.h>

#define BN 8192
#define DIM 512
#define NB  64            // BN / 128 block-rows
#define EPSF 1e-8f

using frag8 = __attribute__((ext_vector_type(8))) short;   // 8 bf16 (4 VGPRs)
using f32x4 = __attribute__((ext_vector_type(4))) float;   // 4 fp32 acc

__device__ inline unsigned short f2bf(float f) {
    union { float f; unsigned int u; } x; x.f = f;
    unsigned int r = (x.u + 0x7FFFu + ((x.u >> 16) & 1u)) >> 16;
    return (unsigned short)r;
}

// Async global->LDS, 16 B per lane, dest = uniform base + lane*16.
__device__ inline void async_copy16(const unsigned short* g, unsigned short* l) {
    __builtin_amdgcn_global_load_lds(
        (const __attribute__((address_space(1))) void*)g,
        (__attribute__((address_space(3))) void*)l,
        16, 0, 0);
}

// One wave per row: L2-normalize and convert to bf16.
__global__ __launch_bounds__(256) void normalize_kernel(
        const float* __restrict__ emb, unsigned short* __restrict__ E) {
    int wave = threadIdx.x >> 6;
    int lane = threadIdx.x & 63;
    int row  = blockIdx.x * 4 + wave;
    const float4* src = (const float4*)(emb + (size_t)row * DIM);
    float4 a = src[lane * 2 + 0];
    float4 b = src[lane * 2 + 1];
    float ss = a.x*a.x + a.y*a.y + a.z*a.z + a.w*a.w
             + b.x*b.x + b.y*b.y + b.z*b.z + b.w*b.w;
    #pragma unroll
    for (int m = 1; m < 64; m <<= 1) ss += __shfl_xor(ss, m, 64);
    float scale = 1.0f / fmaxf(sqrtf(ss), 1e-12f);
    unsigned short u[8];
    u[0] = f2bf(a.x*scale); u[1] = f2bf(a.y*scale);
    u[2] = f2bf(a.z*scale); u[3] = f2bf(a.w*scale);
    u[4] = f2bf(b.x*scale); u[5] = f2bf(b.y*scale);
    u[6] = f2bf(b.z*scale); u[7] = f2bf(b.w*scale);
    uint4 packed;
    packed.x = (unsigned)u[0] | ((unsigned)u[1] << 16);
    packed.y = (unsigned)u[2] | ((unsigned)u[3] << 16);
    packed.z = (unsigned)u[4] | ((unsigned)u[5] << 16);
    packed.w = (unsigned)u[6] | ((unsigned)u[7] << 16);
    *(uint4*)(E + (size_t)row * DIM + lane * 8) = packed;
}

// Upper-triangle 128x128 block tiles, 1D grid of 2080 with triangular decode.
// 4 waves, each 64x64 via 4x4 grid of 16x16x32 MFMA. Double-buffered
// global_load_lds staging (prefetch k+1 after barrier). Fused epilogue:
// w = exp(S-1); masked row sums -> P/N[bj][slab bi]; for off-diagonal blocks
// column sums (symmetry) -> P/N[bi][slab bj]. NO atomics: every slot has a
// unique writer under the triangle decomposition.
__global__ __launch_bounds__(256) void gemm_epi_kernel(
        const unsigned short* __restrict__ E, const int* __restrict__ labels,
        float* __restrict__ P, float* __restrict__ N) {
    constexpr int BI = 128, BK = 32, KITERS = DIM / BK;

    // triangular decode: block-row bi has (64 - bi) tiles, cum(bi)=64bi-bi(bi-1)/2
    int t  = blockIdx.x;
    int bi = (int)(64.5f - sqrtf(64.5f * 64.5f - 2.0f * (float)t));
    while (64 * (bi + 1) - ((bi + 1) * bi) / 2 <= t) ++bi;
    while (64 * bi - (bi * (bi - 1)) / 2 > t) --bi;
    int bj = bi + (t - (64 * bi - (bi * (bi - 1)) / 2));
    const bool diag = (bi == bj);

    __shared__ unsigned short As[2][BI][BK];   // 2 x 8 KB
    __shared__ unsigned short Bs[2][BI][BK];   // 2 x 8 KB
    __shared__ int labI[BI];
    __shared__ int labJ[BI];
    __shared__ float rowP[BI][2], rowN[BI][2]; // per-wave-pair row partials
    __shared__ float colP[BI][2], colN[BI][2];

    const int tid  = threadIdx.x;
    const int i0   = bi * BI;
    const int j0   = bj * BI;
    const int wave = tid >> 6;
    const int lane = tid & 63;
    const int quad = lane >> 4;    // 0..3
    const int lrow = lane & 15;    // 0..15
    const int i_w  = (wave >> 1) * 64;
    const int j_w  = (wave & 1) * 64;

    if (tid < 128)       labI[tid]       = labels[i0 + tid];
    else                 labJ[tid - 128] = labels[j0 + tid - 128];

    f32x4 acc[4][4];
    #pragma unroll
    for (int a = 0; a < 4; ++a)
        #pragma unroll
        for (int b = 0; b < 4; ++b)
            acc[a][b] = (f32x4){0.f, 0.f, 0.f, 0.f};

    // staging geometry: wave covers rows [wave*32, wave*32+32), lane l:
    // row = l>>2, 16B segment = l&3. LDS dest = uniform base + lane*16.
    const int rbase = wave * 32;
    const int rowl  = lane >> 2;
    const int cseg  = (lane & 3) * 8;

    #define STAGE(KK, B)                                                       \
        {                                                                      \
            _Pragma("unroll")                                                  \
            for (int h = 0; h < 2; ++h) {                                      \
                int r = rbase + h * 16;                                        \
                async_copy16(E + (size_t)(i0 + r + rowl) * DIM + (KK) + cseg,  \
                             &As[B][r][0]);                                    \
                async_copy16(E + (size_t)(j0 + r + rowl) * DIM + (KK) + cseg,  \
                             &Bs[B][r][0]);                                    \
            }                                                                  \
        }

    STAGE(0, 0);
    for (int k = 0; k < KITERS; ++k) {
        int b = k & 1;
        __syncthreads();                       // drains vmcnt: buf b ready
        if (k + 1 < KITERS) STAGE((k + 1) * BK, b ^ 1);  // in flight over compute

        frag8 af[4], bf[4];
        #pragma unroll
        for (int tt = 0; tt < 4; ++tt) {
            af[tt] = *(const frag8*)&As[b][i_w + tt * 16 + lrow][quad * 8];
            bf[tt] = *(const frag8*)&Bs[b][j_w + tt * 16 + lrow][quad * 8];
        }
        #pragma unroll
        for (int ti = 0; ti < 4; ++ti)
            #pragma unroll
            for (int tj = 0; tj < 4; ++tj)
                acc[ti][tj] = __builtin_amdgcn_mfma_f32_16x16x32_bf16(
                                  af[ti], bf[tj], acc[ti][tj], 0, 0, 0);
    }

    // Epilogue. C/D layout: col = lane&15, row = quad*4 + reg.
    float psC[4] = {0.f, 0.f, 0.f, 0.f};
    float nsC[4] = {0.f, 0.f, 0.f, 0.f};
    #pragma unroll
    for (int ti = 0; ti < 4; ++ti) {
        #pragma unroll
        for (int reg = 0; reg < 4; ++reg) {
            int irow = i_w + ti * 16 + quad * 4 + reg;
            int li   = labI[irow];
            int gi   = i0 + irow;
            float ps = 0.f, ns = 0.f;
            #pragma unroll
            for (int tj = 0; tj < 4; ++tj) {
                int jcol = j_w + tj * 16 + lrow;
                int lj   = labJ[jcol];
                int gj   = j0 + jcol;
                float w  = __expf(acc[ti][tj][reg] - 1.0f);
                bool same = (li == lj);
                float wp = (same && (gi != gj)) ? w : 0.f;
                float wn = same ? 0.f : w;
                ps += wp;  ns += wn;
                psC[tj] += wp;  nsC[tj] += wn;
            }
            #pragma unroll
            for (int m = 1; m < 16; m <<= 1) {
                ps += __shfl_xor(ps, m, 64);
                ns += __shfl_xor(ns, m, 64);
            }
            if (lrow == 0) {
                rowP[irow][wave & 1] = ps;
                rowN[irow][wave & 1] = ns;
            }
        }
    }
    #pragma unroll
    for (int tj = 0; tj < 4; ++tj) {
        float ps = psC[tj], ns = nsC[tj];
        ps += __shfl_xor(ps, 16, 64);  ns += __shfl_xor(ns, 16, 64);
        ps += __shfl_xor(ps, 32, 64);  ns += __shfl_xor(ns, 32, 64);
        if (lane < 16) {
            int jc = j_w + tj * 16 + lrow;
            colP[jc][wave >> 1] = ps;
            colN[jc][wave >> 1] = ns;
        }
    }
    __syncthreads();
    int r = tid & 127;
    if (tid < 128) {
        P[(size_t)bj * BN + i0 + r] = rowP[r][0] + rowP[r][1];
        N[(size_t)bj * BN + i0 + r] = rowN[r][0] + rowN[r][1];
    } else if (!diag) {
        P[(size_t)bi * BN + j0 + r] = colP[r][0] + colP[r][1];
        N[(size_t)bi * BN + j0 + r] = colN[r][0] + colN[r][1];
    }
    #undef STAGE
}

// Sum the 64 partials per row: pos[i] = sum_c P[c][i].
__global__ __launch_bounds__(256) void reduce_partials(
        const float* __restrict__ P, const float* __restrict__ N,
        float* __restrict__ pos, float* __restrict__ neg) {
    int i = blockIdx.x * 256 + threadIdx.x;
    float p = 0.f, n = 0.f;
    #pragma unroll 4
    for (int c = 0; c < NB; ++c) {
        p += P[(size_t)c * BN + i];
        n += N[(size_t)c * BN + i];
    }
    pos[i] = p;
    neg[i] = n;
}

// Single block: histogram of 128 classes, per-row loss, mean.
__global__ __launch_bounds__(1024) void finalize_kernel(
        const int* __restrict__ labels, const float* __restrict__ pos,
        const float* __restrict__ neg, float* __restrict__ out) {
    __shared__ int cnt[128];
    __shared__ float wsum[16];
    int tid = threadIdx.x;
    if (tid < 128) cnt[tid] = 0;
    __syncthreads();
    for (int i = tid; i < BN; i += 1024) atomicAdd(&cnt[labels[i]], 1);
    __syncthreads();
    float local = 0.f;
    for (int i = tid; i < BN; i += 1024) {
        int c = cnt[labels[i]];
        float pc = (float)(c - 1);
        float nc = (float)(BN - c);
        float pm = pos[i] / fmaxf(pc, 1.0f);
        float nm = neg[i] / fmaxf(nc, 1.0f);
        float v = ((c - 1 > 0) && (BN - c > 0))
                      ? -logf(pm / (pm + nm + EPSF)) : 0.0f;
        local += v;
    }
    #pragma unroll
    for (int m = 1; m < 64; m <<= 1) local += __shfl_xor(local, m, 64);
    if ((tid & 63) == 0) wsum[tid >> 6] = local;
    __syncthreads();
    if (tid < 16) {
        float v = wsum[tid];
        #pragma unroll
        for (int m = 1; m < 16; m <<= 1) v += __shfl_xor(v, m, 64);
        if (tid == 0) out[0] = v / (float)BN;
    }
}

extern "C" void kernel_launch(void* const* d_in, const int* in_sizes, int n_in,
                              void* d_out, int out_size, void* d_ws, size_t ws_size,
                              hipStream_t stream) {
    const float* emb   = (const float*)d_in[0];
    const int* labels  = (const int*)d_in[1];
    float* out         = (float*)d_out;

    // ws layout: E (8 MB bf16) | P (2 MB) | N (2 MB) | pos (32 KB) | neg (32 KB)
    unsigned short* E  = (unsigned short*)d_ws;
    float* P           = (float*)((char*)d_ws + (size_t)BN * DIM * 2);
    float* N           = P + (size_t)NB * BN;
    float* pos         = N + (size_t)NB * BN;
    float* neg         = pos + BN;

    normalize_kernel<<<BN / 4, 256, 0, stream>>>(emb, E);
    gemm_epi_kernel<<<NB * (NB + 1) / 2, 256, 0, stream>>>(E, labels, P, N);
    reduce_partials<<<BN / 256, 256, 0, stream>>>(P, N, pos, neg);
    finalize_kernel<<<1, 1024, 0, stream>>>(labels, pos, neg, out);
}

// Round 4
// 155.842 us; speedup vs baseline: 1.7201x; 1.0040x over previous
//
#include <hip/hip_runtime.h>
#include <hip/hip_bf16.h>

#define BN 8192
#define DIM 512
#define NB  64            // BN / 128 block-rows
#define EPSF 1e-8f

using v8i   = __attribute__((ext_vector_type(8))) int;
using v4i   = __attribute__((ext_vector_type(4))) int;
using f32x4 = __attribute__((ext_vector_type(4))) float;

// Async global->LDS, 16 B per lane, dest = uniform base + lane*16.
__device__ inline void async_copy16(const void* g, void* l) {
    __builtin_amdgcn_global_load_lds(
        (const __attribute__((address_space(1))) void*)g,
        (__attribute__((address_space(3))) void*)l,
        16, 0, 0);
}

// One wave per row: L2-normalize, scale by 4, convert to fp8 e4m3.
// (x4 pre-scale keeps values in e4m3 normal range; S = acc/16 in epilogue.)
__global__ __launch_bounds__(256) void normalize_kernel(
        const float* __restrict__ emb, unsigned char* __restrict__ E) {
    int wave = threadIdx.x >> 6;
    int lane = threadIdx.x & 63;
    int row  = blockIdx.x * 4 + wave;
    const float4* src = (const float4*)(emb + (size_t)row * DIM);
    float4 a = src[lane];        // elems 4*lane .. +4       (coalesced)
    float4 b = src[lane + 64];   // elems 256+4*lane .. +4   (coalesced)
    float ss = a.x*a.x + a.y*a.y + a.z*a.z + a.w*a.w
             + b.x*b.x + b.y*b.y + b.z*b.z + b.w*b.w;
    #pragma unroll
    for (int m = 1; m < 64; m <<= 1) ss += __shfl_xor(ss, m, 64);
    float s4 = 4.0f / fmaxf(sqrtf(ss), 1e-12f);
    int pa = __builtin_amdgcn_cvt_pk_fp8_f32(a.x*s4, a.y*s4, 0, false);
    pa     = __builtin_amdgcn_cvt_pk_fp8_f32(a.z*s4, a.w*s4, pa, true);
    int pb = __builtin_amdgcn_cvt_pk_fp8_f32(b.x*s4, b.y*s4, 0, false);
    pb     = __builtin_amdgcn_cvt_pk_fp8_f32(b.z*s4, b.w*s4, pb, true);
    unsigned char* rowp = E + (size_t)row * DIM;
    ((unsigned*)rowp)[lane]       = (unsigned)pa;   // bytes 4*lane
    ((unsigned*)(rowp + 256))[lane] = (unsigned)pb; // bytes 256+4*lane
}

// Upper-triangle 128x128 tiles, 1D grid (2080), triangular decode.
// fp8 e4m3, MX-scaled MFMA 16x16x128 (scale=1.0 -> 0x7F), BK=128 -> only
// 4 K-iterations (4 barrier drains vs 16). Double-buffered global_load_lds.
// XOR chunk swizzle (16B chunks, chunk^row within 8-row groups) makes the
// ds_read_b128 fragment loads <=2-way bank-conflicted (free), while keeping
// global fetches within the same 128B line (coalesced) and respecting the
// fixed lane->LDS mapping of global_load_lds.
__global__ __launch_bounds__(256) void gemm_epi_kernel(
        const unsigned char* __restrict__ E, const int* __restrict__ labels,
        float* __restrict__ P, float* __restrict__ N) {
    constexpr int BI = 128, BK = 128, KITERS = DIM / BK;   // 4

    int t  = blockIdx.x;
    int bi = (int)(64.5f - sqrtf(64.5f * 64.5f - 2.0f * (float)t));
    while (64 * (bi + 1) - ((bi + 1) * bi) / 2 <= t) ++bi;
    while (64 * bi - (bi * (bi - 1)) / 2 > t) --bi;
    int bj = bi + (t - (64 * bi - (bi * (bi - 1)) / 2));
    const bool diag = (bi == bj);

    __shared__ unsigned char As[2][BI][BK];   // 2 x 16 KB
    __shared__ unsigned char Bs[2][BI][BK];   // 2 x 16 KB
    __shared__ int labI[BI];
    __shared__ int labJ[BI];
    __shared__ float rowP[BI][2], rowN[BI][2];
    __shared__ float colP[BI][2], colN[BI][2];

    const int tid  = threadIdx.x;
    const int i0   = bi * BI;
    const int j0   = bj * BI;
    const int wave = tid >> 6;
    const int lane = tid & 63;
    const int quad = lane >> 4;    // 0..3
    const int lrow = lane & 15;    // 0..15
    const int i_w  = (wave >> 1) * 64;
    const int j_w  = (wave & 1) * 64;

    if (tid < 128)       labI[tid]       = labels[i0 + tid];
    else                 labJ[tid - 128] = labels[j0 + tid - 128];

    f32x4 acc[4][4];
    #pragma unroll
    for (int a = 0; a < 4; ++a)
        #pragma unroll
        for (int b = 0; b < 4; ++b)
            acc[a][b] = (f32x4){0.f, 0.f, 0.f, 0.f};

    // Staging: wave covers rows [wave*32, wave*32+32) as 4 instrs of 8 rows.
    // Lane l: local row lr=l>>3, LDS chunk ck=l&7; fetch global chunk ck^lr.
    const int lr = lane >> 3;
    const int gc = (lane & 7) ^ lr;

    #define STAGE(KK, B)                                                       \
        {                                                                      \
            _Pragma("unroll")                                                  \
            for (int h = 0; h < 4; ++h) {                                      \
                int r0 = wave * 32 + h * 8;                                    \
                async_copy16(E + (size_t)(i0 + r0 + lr) * DIM + (KK) + gc*16,  \
                             &As[B][r0][0]);                                   \
                async_copy16(E + (size_t)(j0 + r0 + lr) * DIM + (KK) + gc*16,  \
                             &Bs[B][r0][0]);                                   \
            }                                                                  \
        }

    STAGE(0, 0);
    for (int k = 0; k < KITERS; ++k) {
        int b = k & 1;
        __syncthreads();                                  // buf b ready
        if (k + 1 < KITERS) STAGE((k + 1) * BK, b ^ 1);   // prefetch in flight

        // Fragment loads: lane (row lrow, k-block quad) needs global chunks
        // quad*2, quad*2+1 (32 consecutive k-bytes). LDS chunk = gc ^ (R&7).
        v8i af[4], bf[4];
        #pragma unroll
        for (int tt = 0; tt < 4; ++tt) {
            {
                int R  = i_w + tt * 16 + lrow;
                const v4i* rp = (const v4i*)&As[b][R][0];
                int sw = R & 7;
                v4i lo = rp[(quad * 2) ^ sw];
                v4i hi = rp[(quad * 2 + 1) ^ sw];
                af[tt] = (v8i){lo[0], lo[1], lo[2], lo[3],
                               hi[0], hi[1], hi[2], hi[3]};
            }
            {
                int R  = j_w + tt * 16 + lrow;
                const v4i* rp = (const v4i*)&Bs[b][R][0];
                int sw = R & 7;
                v4i lo = rp[(quad * 2) ^ sw];
                v4i hi = rp[(quad * 2 + 1) ^ sw];
                bf[tt] = (v8i){lo[0], lo[1], lo[2], lo[3],
                               hi[0], hi[1], hi[2], hi[3]};
            }
        }
        #pragma unroll
        for (int ti = 0; ti < 4; ++ti)
            #pragma unroll
            for (int tj = 0; tj < 4; ++tj)
                acc[ti][tj] = __builtin_amdgcn_mfma_scale_f32_16x16x128_f8f6f4(
                                  af[ti], bf[tj], acc[ti][tj],
                                  0, 0,                 // cbsz/blgp: fp8 e4m3
                                  0, 0x7F7F7F7F,        // A scale = 1.0
                                  0, 0x7F7F7F7F);       // B scale = 1.0
    }

    // Epilogue. C/D layout: col = lane&15, row = quad*4 + reg. acc = 16*S.
    float psC[4] = {0.f, 0.f, 0.f, 0.f};
    float nsC[4] = {0.f, 0.f, 0.f, 0.f};
    #pragma unroll
    for (int ti = 0; ti < 4; ++ti) {
        #pragma unroll
        for (int reg = 0; reg < 4; ++reg) {
            int irow = i_w + ti * 16 + quad * 4 + reg;
            int li   = labI[irow];
            int gi   = i0 + irow;
            float ps = 0.f, ns = 0.f;
            #pragma unroll
            for (int tj = 0; tj < 4; ++tj) {
                int jcol = j_w + tj * 16 + lrow;
                int lj   = labJ[jcol];
                int gj   = j0 + jcol;
                float w  = __expf(fmaf(acc[ti][tj][reg], 0.0625f, -1.0f));
                bool same = (li == lj);
                float wp = (same && (gi != gj)) ? w : 0.f;
                float wn = same ? 0.f : w;
                ps += wp;  ns += wn;
                psC[tj] += wp;  nsC[tj] += wn;
            }
            #pragma unroll
            for (int m = 1; m < 16; m <<= 1) {
                ps += __shfl_xor(ps, m, 64);
                ns += __shfl_xor(ns, m, 64);
            }
            if (lrow == 0) {
                rowP[irow][wave & 1] = ps;
                rowN[irow][wave & 1] = ns;
            }
        }
    }
    #pragma unroll
    for (int tj = 0; tj < 4; ++tj) {
        float ps = psC[tj], ns = nsC[tj];
        ps += __shfl_xor(ps, 16, 64);  ns += __shfl_xor(ns, 16, 64);
        ps += __shfl_xor(ps, 32, 64);  ns += __shfl_xor(ns, 32, 64);
        if (lane < 16) {
            int jc = j_w + tj * 16 + lrow;
            colP[jc][wave >> 1] = ps;
            colN[jc][wave >> 1] = ns;
        }
    }
    __syncthreads();
    int r = tid & 127;
    if (tid < 128) {
        P[(size_t)bj * BN + i0 + r] = rowP[r][0] + rowP[r][1];
        N[(size_t)bj * BN + i0 + r] = rowN[r][0] + rowN[r][1];
    } else if (!diag) {
        P[(size_t)bi * BN + j0 + r] = colP[r][0] + colP[r][1];
        N[(size_t)bi * BN + j0 + r] = colN[r][0] + colN[r][1];
    }
    #undef STAGE
}

// Sum the 64 partials per row: pos[i] = sum_c P[c][i].
__global__ __launch_bounds__(256) void reduce_partials(
        const float* __restrict__ P, const float* __restrict__ N,
        float* __restrict__ pos, float* __restrict__ neg) {
    int i = blockIdx.x * 256 + threadIdx.x;
    float p = 0.f, n = 0.f;
    #pragma unroll 4
    for (int c = 0; c < NB; ++c) {
        p += P[(size_t)c * BN + i];
        n += N[(size_t)c * BN + i];
    }
    pos[i] = p;
    neg[i] = n;
}

// Single block: histogram of 128 classes, per-row loss, mean.
__global__ __launch_bounds__(1024) void finalize_kernel(
        const int* __restrict__ labels, const float* __restrict__ pos,
        const float* __restrict__ neg, float* __restrict__ out) {
    __shared__ int cnt[128];
    __shared__ float wsum[16];
    int tid = threadIdx.x;
    if (tid < 128) cnt[tid] = 0;
    __syncthreads();
    for (int i = tid; i < BN; i += 1024) atomicAdd(&cnt[labels[i]], 1);
    __syncthreads();
    float local = 0.f;
    for (int i = tid; i < BN; i += 1024) {
        int c = cnt[labels[i]];
        float pc = (float)(c - 1);
        float nc = (float)(BN - c);
        float pm = pos[i] / fmaxf(pc, 1.0f);
        float nm = neg[i] / fmaxf(nc, 1.0f);
        float v = ((c - 1 > 0) && (BN - c > 0))
                      ? -logf(pm / (pm + nm + EPSF)) : 0.0f;
        local += v;
    }
    #pragma unroll
    for (int m = 1; m < 64; m <<= 1) local += __shfl_xor(local, m, 64);
    if ((tid & 63) == 0) wsum[tid >> 6] = local;
    __syncthreads();
    if (tid < 16) {
        float v = wsum[tid];
        #pragma unroll
        for (int m = 1; m < 16; m <<= 1) v += __shfl_xor(v, m, 64);
        if (tid == 0) out[0] = v / (float)BN;
    }
}

extern "C" void kernel_launch(void* const* d_in, const int* in_sizes, int n_in,
                              void* d_out, int out_size, void* d_ws, size_t ws_size,
                              hipStream_t stream) {
    const float* emb   = (const float*)d_in[0];
    const int* labels  = (const int*)d_in[1];
    float* out         = (float*)d_out;

    // ws layout (E region kept 8 MB-sized for layout stability; fp8 uses 4 MB):
    // E (8 MB) | P (2 MB) | N (2 MB) | pos (32 KB) | neg (32 KB)
    unsigned char* E   = (unsigned char*)d_ws;
    float* P           = (float*)((char*)d_ws + (size_t)BN * DIM * 2);
    float* N           = P + (size_t)NB * BN;
    float* pos         = N + (size_t)NB * BN;
    float* neg         = pos + BN;

    normalize_kernel<<<BN / 4, 256, 0, stream>>>(emb, E);
    gemm_epi_kernel<<<NB * (NB + 1) / 2, 256, 0, stream>>>(E, labels, P, N);
    reduce_partials<<<BN / 256, 256, 0, stream>>>(P, N, pos, neg);
    finalize_kernel<<<1, 1024, 0, stream>>>(labels, pos, neg, out);
}